// Round 14
// baseline (408.639 us; speedup 1.0000x reference)
//
#include <hip/hip_runtime.h>
#include <hip/hip_fp16.h>
#include <math.h>

#define NH     16
#define HD     64
#define S_LEN  2048
#define THD_   1024
// exp(s*0.125) = exp2(s * 0.125 * log2(e))
#define SCALE_LOG2E 0.18033688011112042f

typedef __fp16 f16x8 __attribute__((ext_vector_type(8)));
typedef __fp16 f16x4 __attribute__((ext_vector_type(4)));
typedef __fp16 f16x2 __attribute__((ext_vector_type(2)));
typedef float  f32x4 __attribute__((ext_vector_type(4)));

#define GLDS16(src, dst)                                                      \
  __builtin_amdgcn_global_load_lds(                                           \
      (const __attribute__((address_space(1))) unsigned int*)(const void*)(src), \
      (__attribute__((address_space(3))) unsigned int*)(void*)(dst), 16, 0, 0)

// ws layout (half-elements; total 41,943,040 B, proven safe):
//   region A @ 0        : q_h  8,388,608   [b][comp][h][s][hd]  (PRE-SCALED by SCALE_LOG2E)
//   region B @ 8388608  : k_h  8,388,608   same layout (unscaled)
//   region C @ 16777216 : vt_h 4,194,304   [b][h][hd][s]
// time-shared:
//   WqT fp16 @ B[0:2097152)        (dead once q-GEMM done; k-GEMM overwrites)
//   WkT fp16 @ C[0:2097152)        (dead once k-GEMM done; v-GEMM overwrites)
//   rope tab fp32[2048][32][2] @ C[2097152:2359296) (dead before v-GEMM)
//   WoT @ A[0:1048576), gn_h @ A[1048576:5242880)   (A dead after attn)

// ---------------------------------------------------------------------------
// Shared weight-transpose body: W[k][n] fp32 -> WT[n][k] fp16.
// ---------------------------------------------------------------------------
__device__ inline void wt_body(const float* __restrict__ W,
                               __half* __restrict__ WT, int id, int nmask,
                               int nshift) {
  int n = id & nmask;
  int k8 = (id >> nshift) * 8;
  int N = nmask + 1;
  f16x8 h;
#pragma unroll
  for (int j = 0; j < 8; ++j)
    h[j] = (__fp16)W[(size_t)(k8 + j) * N + n];
  *(f16x8*)(WT + (size_t)n * 1024 + k8) = h;
}

// ---------------------------------------------------------------------------
// Fused prep: blocks [0,1024) transpose Wq; [1024,2048) transpose Wk;
// [2048,2304) fill the RoPE cos/sin table tab[s][p] (2048 x 32).
// ---------------------------------------------------------------------------
__global__ __launch_bounds__(256) void prep_kernel(
    const float* __restrict__ Wq, const float* __restrict__ Wk,
    __half* __restrict__ WqT, __half* __restrict__ WkT,
    float2* __restrict__ tab) {
  int bid = blockIdx.x;
  int t = threadIdx.x;
  if (bid < 1024) {
    wt_body(Wq, WqT, bid * 256 + t, 2047, 11);
  } else if (bid < 2048) {
    wt_body(Wk, WkT, (bid - 1024) * 256 + t, 2047, 11);
  } else {
    int id = (bid - 2048) * 256 + t;  // 65536
    int p = id & 31;
    int s = id >> 5;
    float inv = expf(-0.28782313662425574f * (float)p);
    float sn, cs;
    sincosf((float)s * inv, &sn, &cs);
    tab[id] = make_float2(cs, sn);
  }
}

// ---------------------------------------------------------------------------
// fp16 MFMA GEMM, R14: ASYNC FRAGMENT-MAJOR STAGING (mechanism verified on
// attn in R13: the global->VGPR->cvt->ds_write->barrier chain exposes HBM
// latency because the compiler sinks loads toward use; global_load_lds is
// fire-and-forget).  LDS is fragment-major: each 1KB chunk is one MFMA
// fragment tile in lane order -> async dst is wave-uniform + lane*16B and
// LDS reads are lane-linear (conflict-free).  A = x fp32 stages as fp32
// chunks (2 per fragment); f32->f16 cast moves into the fragment read.
// B = WT fp16 stages async directly.  Single-buffer 2-barrier structure
// (m97 pattern; inter-block wave overlap hides the drain at 4 blocks/CU).
// 128m x 64n tile, BK=64; wave w: rows [w*32,w*32+32) x 64 cols.
// MODE 0: A = x fp32, B = WT fp16; fused-RoPE epilogue
// MODE 1: MODE 0 + output scaled by SCALE_LOG2E (q path)
// MODE 2: A = x fp32 async, B = raw Wv fp32 column gather (can't async;
//         written fragment-major); fp16 to vt [b][h][hd][s]
// MODE 3: A = gn_h fp16 async, B = WoT fp16 async; fp32 row-major out
// ---------------------------------------------------------------------------
template <int MODE>
__global__ __launch_bounds__(256) void mfma_gemm(const void* __restrict__ Ap,
                                                 const void* __restrict__ Bp,
                                                 void* __restrict__ Cp,
                                                 const float2* __restrict__ tab) {
  // A chunks: fp32 [mt2][ks][half][lane][4] = 32KB, or fp16 [mt2][ks][lane][8]
  __shared__ __attribute__((aligned(16))) char AsRaw[32768];
  __shared__ __half Bs[4][2][64][8];  // 8KB fragment-major
  typedef float  AFrag32[2][2][64][4];
  typedef __half AFrag16[2][64][8];
  AFrag32* As32 = (AFrag32*)AsRaw;
  AFrag16* As16 = (AFrag16*)AsRaw;

  const int t = threadIdx.x;
  const int w = t >> 6, lane = t & 63;
  const int quad = lane >> 4, lqi = lane & 15;
  const int n0 = blockIdx.x * 64, m0 = blockIdx.y * 128;

  f32x4 acc[2][4];
#pragma unroll
  for (int mt = 0; mt < 2; ++mt)
#pragma unroll
    for (int nt = 0; nt < 4; ++nt) acc[mt][nt] = (f32x4){0.f, 0.f, 0.f, 0.f};

  const int gn_ = t & 63;          // MODE2 gather: n within tile
  const int gk0 = (t >> 6) * 8;    // MODE2 gather: k offset within ks (=w*8)

  for (int k0 = 0; k0 < 1024; k0 += 64) {
    if (k0) __syncthreads();
    // ---- async staging (fire-and-forget; barrier below drains vmcnt) ----
    if (MODE == 3) {
      const __half* A16 = (const __half*)Ap;
      const __half* B16 = (const __half*)Bp;
#pragma unroll
      for (int ci = 0; ci < 6; ++ci) {
        int c = w + ci * 4;  // 16 A chunks + 8 B chunks
        if (c < 16) {
          int mt2 = c >> 1, ks = c & 1;
          GLDS16(A16 + (size_t)(m0 + mt2 * 16 + lqi) * 1024 + k0 + ks * 32 +
                     quad * 8,
                 &As16[mt2][ks][0][0]);
        } else {
          int cc = c - 16, nt2 = cc >> 1, ks = cc & 1;
          GLDS16(B16 + (size_t)(n0 + nt2 * 16 + lqi) * 1024 + k0 + ks * 32 +
                     quad * 8,
                 &Bs[nt2][ks][0][0]);
        }
      }
    } else if (MODE == 2) {
      const float* A32 = (const float*)Ap;
#pragma unroll
      for (int ci = 0; ci < 8; ++ci) {  // 32 A chunks
        int c = w + ci * 4;
        int mt2 = c >> 2, ks = (c >> 1) & 1, half = c & 1;
        GLDS16(A32 + (size_t)(m0 + mt2 * 16 + lqi) * 1024 + k0 + ks * 32 +
                   quad * 8 + half * 4,
               &As32[mt2][ks][half][0][0]);
      }
      // B: Wv column gather (non-contiguous per-lane; manual, frag-major)
      const float* B32 = (const float*)Bp;  // Wv row-major [k][1024]
#pragma unroll
      for (int p = 0; p < 2; ++p) {
        f16x8 h;
#pragma unroll
        for (int j = 0; j < 8; ++j)
          h[j] = (__fp16)B32[(size_t)(k0 + p * 32 + gk0 + j) * 1024 + n0 + gn_];
        *(f16x8*)&Bs[gn_ >> 4][p][w * 16 + (gn_ & 15)][0] = h;
      }
    } else {
      const float* A32 = (const float*)Ap;
      const __half* B16 = (const __half*)Bp;  // WT [n][k]
#pragma unroll
      for (int ci = 0; ci < 10; ++ci) {  // 32 A chunks + 8 B chunks
        int c = w + ci * 4;
        if (c < 32) {
          int mt2 = c >> 2, ks = (c >> 1) & 1, half = c & 1;
          GLDS16(A32 + (size_t)(m0 + mt2 * 16 + lqi) * 1024 + k0 + ks * 32 +
                     quad * 8 + half * 4,
                 &As32[mt2][ks][half][0][0]);
        } else {
          int cc = c - 32, nt2 = cc >> 1, ks = cc & 1;
          GLDS16(B16 + (size_t)(n0 + nt2 * 16 + lqi) * 1024 + k0 + ks * 32 +
                     quad * 8,
                 &Bs[nt2][ks][0][0]);
        }
      }
    }
    __syncthreads();
    // ---- MFMA (fragment reads are lane-linear; A casts f32->f16 here) ----
#pragma unroll
    for (int ks = 0; ks < 2; ++ks) {
      f16x8 af[2], bf[4];
#pragma unroll
      for (int mt = 0; mt < 2; ++mt) {
        if (MODE == 3) {
          af[mt] = *(const f16x8*)&As16[w * 2 + mt][ks][lane][0];
        } else {
          f32x4 lo = *(const f32x4*)&As32[w * 2 + mt][ks][0][lane][0];
          f32x4 hi = *(const f32x4*)&As32[w * 2 + mt][ks][1][lane][0];
          f16x8 h;
          h[0] = (__fp16)lo[0]; h[1] = (__fp16)lo[1];
          h[2] = (__fp16)lo[2]; h[3] = (__fp16)lo[3];
          h[4] = (__fp16)hi[0]; h[5] = (__fp16)hi[1];
          h[6] = (__fp16)hi[2]; h[7] = (__fp16)hi[3];
          af[mt] = h;
        }
      }
#pragma unroll
      for (int nt = 0; nt < 4; ++nt)
        bf[nt] = *(const f16x8*)&Bs[nt][ks][lane][0];
#pragma unroll
      for (int mt = 0; mt < 2; ++mt)
#pragma unroll
        for (int nt = 0; nt < 4; ++nt)
          acc[mt][nt] = __builtin_amdgcn_mfma_f32_16x16x32_f16(
              af[mt], bf[nt], acc[mt][nt], 0, 0, 0);
    }
  }

  // ---- epilogue (unchanged) ----
  const int b = m0 >> 11;
  const int wm = w * 32;
  const int s0 = (m0 & 2047) + wm + quad * 4;
  if (MODE == 0 || MODE == 1) {
    __half* dst = (__half*)Cp;
    const int comp = n0 >> 10, hh = (n0 >> 6) & 15;
    __half* base = dst + ((size_t)(b * 2 + comp) * NH + hh) * (size_t)S_LEN * HD;
#pragma unroll
    for (int nt = 0; nt < 2; ++nt) {
      int p = nt * 16 + lqi;
#pragma unroll
      for (int mt = 0; mt < 2; ++mt) {
#pragma unroll
        for (int i = 0; i < 4; ++i) {
          int s = s0 + mt * 16 + i;
          float2 cs = tab[s * 32 + p];
          float x1 = acc[mt][nt][i], x2 = acc[mt][nt + 2][i];
          float y1 = x1 * cs.x - x2 * cs.y;
          float y2 = x2 * cs.x + x1 * cs.y;
          if (MODE == 1) { y1 *= SCALE_LOG2E; y2 *= SCALE_LOG2E; }
          base[(size_t)s * HD + p] = __float2half(y1);
          base[(size_t)s * HD + p + 32] = __float2half(y2);
        }
      }
    }
  } else if (MODE == 2) {
    __half* vt = (__half*)Cp;
    const int hh = n0 >> 6;
#pragma unroll
    for (int nt = 0; nt < 4; ++nt) {
      int hd = nt * 16 + lqi;
      __half* base = vt + (((size_t)b * NH + hh) * HD + hd) * S_LEN;
#pragma unroll
      for (int mt = 0; mt < 2; ++mt) {
        f16x4 hv;
#pragma unroll
        for (int i = 0; i < 4; ++i) hv[i] = (__fp16)acc[mt][nt][i];
        *(f16x4*)(base + s0 + mt * 16) = hv;
      }
    }
  } else {
    float* Co = (float*)Cp;
#pragma unroll
    for (int mt = 0; mt < 2; ++mt)
#pragma unroll
      for (int i = 0; i < 4; ++i) {
        int m = m0 + wm + mt * 16 + quad * 4 + i;
#pragma unroll
        for (int nt = 0; nt < 4; ++nt)
          Co[(size_t)m * 1024 + n0 + nt * 16 + lqi] = acc[mt][nt][i];
      }
  }
}

// ---------------------------------------------------------------------------
// Differential attention, R13 (MEASURED WIN, unchanged): async global->LDS
// staging via global_load_lds width=16; 108.5 -> 95.2us, MfmaUtil 26->30.7,
// traffic invariant.  K dst wave-uniform + lane*16B; V linear LDS dst with
// XOR swizzle moved into the per-lane GLOBAL source address; read-side
// swizzle unchanged.  One barrier/kt; register-P x32 PV via custom key
// enumeration; scale folded into q.  LDS 48KB, 2 blocks/CU.
// ---------------------------------------------------------------------------
__global__ __launch_bounds__(256, 2) void attn_kernel(
    const __half* __restrict__ q_h, const __half* __restrict__ k_h,
    const __half* __restrict__ vt_h, float* __restrict__ out,
    const float* __restrict__ lq1, const float* __restrict__ lk1,
    const float* __restrict__ lq2, const float* __restrict__ lk2,
    const float* __restrict__ lam_init_p) {
  // K: 16 chunks x 512 halves, chunk = str*8 + mt*2 + ks, addr lane*8.
  // V: [hd 0..63][key 0..63], XOR-swizzled 16B slots within each 128B row
  //    (swizzle applied via the global source address; LDS write is linear).
  __shared__ __half Ks[2][16][512];      // 32 KB
  __shared__ __half Vs[2][64][64];       // 16 KB

  const int t = threadIdx.x;
  const int w = t >> 6, lane = t & 63;
  const int quad = lane >> 4, lqi = lane & 15;
  const int r7 = lane & 7;
  const int qt = blockIdx.x;   // 0..15 (128-query tiles)
  const int bh = blockIdx.y;   // 0..31
  const int b = bh >> 4, h = bh & 15;

  const size_t c1 = ((size_t)(b * 2 + 0) * NH + h) * (size_t)S_LEN * HD;
  const size_t c2 = ((size_t)(b * 2 + 1) * NH + h) * (size_t)S_LEN * HD;
  const size_t vtb = ((size_t)b * NH + h) * (size_t)HD * S_LEN;
  const int q0 = qt * 128 + w * 32;

  f16x8 qf[2][2][2];  // [stream][nt][ks]; q pre-scaled by SCALE_LOG2E
#pragma unroll
  for (int nt = 0; nt < 2; ++nt)
#pragma unroll
    for (int ks = 0; ks < 2; ++ks) {
      size_t a = (size_t)(q0 + nt * 16 + lqi) * HD + ks * 32 + quad * 8;
      qf[0][nt][ks] = *(const f16x8*)(q_h + c1 + a);
      qf[1][nt][ks] = *(const f16x8*)(q_h + c2 + a);
    }

  f32x4 O[2][4][2];  // [stream][hd-chunk][nt]
#pragma unroll
  for (int s = 0; s < 2; ++s)
#pragma unroll
    for (int hm = 0; hm < 4; ++hm)
#pragma unroll
      for (int nt = 0; nt < 2; ++nt) O[s][hm][nt] = (f32x4){0.f, 0.f, 0.f, 0.f};
  float lsum[2][2] = {{0.f, 0.f}, {0.f, 0.f}};

  // async staging: 24 chunks (16 K + 8 V); wave w owns c = w + ci*4.
  auto stage = [&](int c, int k0, int buf) {
    const __half* src;
    __half* dst;
    if (c < 16) {
      int str = c >> 3, mt = (c >> 1) & 3, ks = c & 1;
      src = k_h + (str ? c2 : c1) + (size_t)(k0 + mt * 16 + lqi) * HD +
            ks * 32 + quad * 8;
      dst = &Ks[buf][c][0];
    } else {
      int cc = c - 16;  // V chunk: rows [cc*8, cc*8+8), 64 keys
      src = vt_h + vtb + (size_t)(cc * 8 + (lane >> 3)) * S_LEN + k0 +
            ((lane & 7) ^ (lane >> 3)) * 8;
      dst = &Vs[buf][cc * 8][0];
    }
    GLDS16(src, dst);
  };

  // prologue: stage tile 0 into buffer 0
#pragma unroll
  for (int ci = 0; ci < 6; ++ci) stage(w + ci * 4, 0, 0);
  __syncthreads();

  for (int kt = 0; kt < 32; ++kt) {
    const int cur = kt & 1;
    if (kt < 31) {  // fire-and-forget async loads for tile kt+1
#pragma unroll
      for (int ci = 0; ci < 6; ++ci) stage(w + ci * 4, (kt + 1) * 64, cur ^ 1);
    }

#pragma unroll
    for (int g = 0; g < 2; ++g) {  // 32-key groups (score tiles 2g, 2g+1)
      // ---- V fragments in permuted key order (2 b64 each, swizzle-read) ---
      f16x8 vf[4];
#pragma unroll
      for (int hm = 0; hm < 4; ++hm) {
        const __half* vrow = &Vs[cur][hm * 16 + lqi][0];
        int s0 = (g * 4 + (quad >> 1)) ^ r7;      // keys g*32 + quad*4 ..
        int s1 = (g * 4 + 2 + (quad >> 1)) ^ r7;  // keys g*32+16 + quad*4 ..
        union { f16x8 v8; f16x4 v4[2]; } u;
        u.v4[0] = *(const f16x4*)(vrow + s0 * 8 + (quad & 1) * 4);
        u.v4[1] = *(const f16x4*)(vrow + s1 * 8 + (quad & 1) * 4);
        vf[hm] = u.v8;
      }
      // ---- scores + exp for tiles 2g and 2g+1; B-frag stays in-lane ----
      f16x8 bfrag[2][2];
#pragma unroll
      for (int str = 0; str < 2; ++str) {
        f16x8 kf00 = *(const f16x8*)&Ks[cur][str * 8 + g * 4 + 0][lane * 8];
        f16x8 kf01 = *(const f16x8*)&Ks[cur][str * 8 + g * 4 + 1][lane * 8];
        f16x8 kf10 = *(const f16x8*)&Ks[cur][str * 8 + g * 4 + 2][lane * 8];
        f16x8 kf11 = *(const f16x8*)&Ks[cur][str * 8 + g * 4 + 3][lane * 8];
#pragma unroll
        for (int nt = 0; nt < 2; ++nt) {
          f32x4 sa = (f32x4){0.f, 0.f, 0.f, 0.f};
          f32x4 sb = (f32x4){0.f, 0.f, 0.f, 0.f};
          sa = __builtin_amdgcn_mfma_f32_16x16x32_f16(kf00, qf[str][nt][0], sa,
                                                      0, 0, 0);
          sa = __builtin_amdgcn_mfma_f32_16x16x32_f16(kf01, qf[str][nt][1], sa,
                                                      0, 0, 0);
          sb = __builtin_amdgcn_mfma_f32_16x16x32_f16(kf10, qf[str][nt][0], sb,
                                                      0, 0, 0);
          sb = __builtin_amdgcn_mfma_f32_16x16x32_f16(kf11, qf[str][nt][1], sb,
                                                      0, 0, 0);
          float ea0 = __builtin_amdgcn_exp2f(sa[0]);
          float ea1 = __builtin_amdgcn_exp2f(sa[1]);
          float ea2 = __builtin_amdgcn_exp2f(sa[2]);
          float ea3 = __builtin_amdgcn_exp2f(sa[3]);
          float eb0 = __builtin_amdgcn_exp2f(sb[0]);
          float eb1 = __builtin_amdgcn_exp2f(sb[1]);
          float eb2 = __builtin_amdgcn_exp2f(sb[2]);
          float eb3 = __builtin_amdgcn_exp2f(sb[3]);
          lsum[str][nt] += ((ea0 + ea1) + (ea2 + ea3)) +
                           ((eb0 + eb1) + (eb2 + eb3));
          union { f16x8 v; f16x2 h2[4]; } pu;
          pu.h2[0] = __builtin_amdgcn_cvt_pkrtz(ea0, ea1);
          pu.h2[1] = __builtin_amdgcn_cvt_pkrtz(ea2, ea3);
          pu.h2[2] = __builtin_amdgcn_cvt_pkrtz(eb0, eb1);
          pu.h2[3] = __builtin_amdgcn_cvt_pkrtz(eb2, eb3);
          bfrag[str][nt] = pu.v;
        }
      }
      // ---- PV: full-rate x32 MFMAs, P fragment straight from registers ----
#pragma unroll
      for (int hm = 0; hm < 4; ++hm)
#pragma unroll
        for (int str = 0; str < 2; ++str)
#pragma unroll
          for (int nt = 0; nt < 2; ++nt)
            O[str][hm][nt] = __builtin_amdgcn_mfma_f32_16x16x32_f16(
                vf[hm], bfrag[str][nt], O[str][hm][nt], 0, 0, 0);
    }

    if (kt < 31) __syncthreads();  // drains vmcnt -> tile kt+1 visible
  }

  const float lam0 = lam_init_p[0];
  const float lam = expf(lq1[h] * lk1[h]) - expf(lq2[h] * lk2[h]) + lam0;
#pragma unroll
  for (int str = 0; str < 2; ++str)
#pragma unroll
    for (int nt = 0; nt < 2; ++nt) {
      float v = lsum[str][nt];
      v += __shfl_xor(v, 16);
      v += __shfl_xor(v, 32);
      lsum[str][nt] = v;
    }
#pragma unroll
  for (int nt = 0; nt < 2; ++nt) {
    float il1 = 1.f / lsum[0][nt];
    float il2 = lam / lsum[1][nt];
    int q = q0 + nt * 16 + lqi;
#pragma unroll
    for (int hm = 0; hm < 4; ++hm) {
      f32x4 o;
#pragma unroll
      for (int i = 0; i < 4; ++i)
        o[i] = O[0][hm][nt][i] * il1 - O[1][hm][nt][i] * il2;
      *(f32x4*)(out + ((size_t)(b * S_LEN + q)) * THD_ + h * HD + hm * 16 +
                quad * 4) = o;
    }
  }
}

// ---------------------------------------------------------------------------
// Fused GroupNorm + Wo transpose. Blocks [0,16384): GroupNorm over 64-elem
// head groups (d_out fp32 -> gn_h fp16, * (1-lambda_init)); blocks
// [16384,16896): transpose Wo fp32 -> WoT fp16 [n][k].
// ---------------------------------------------------------------------------
__global__ __launch_bounds__(256) void gn_wt_kernel(
    const float* __restrict__ src, __half* __restrict__ dst,
    const float* __restrict__ gw, const float* __restrict__ gb,
    const float* __restrict__ lam_init_p, const float* __restrict__ Wo,
    __half* __restrict__ WoT) {
  if (blockIdx.x >= 16384) {
    wt_body(Wo, WoT, (blockIdx.x - 16384) * 256 + threadIdx.x, 1023, 10);
    return;
  }
  int g = blockIdx.x * 4 + (threadIdx.x >> 6);
  int lane = threadIdx.x & 63;
  float v = src[(size_t)g * 64 + lane];
  float s = v, sq = v * v;
#pragma unroll
  for (int off = 32; off; off >>= 1) {
    s += __shfl_xor(s, off);
    sq += __shfl_xor(sq, off);
  }
  float mean = s * (1.f / 64.f);
  float var = sq * (1.f / 64.f) - mean * mean;
  float rs = rsqrtf(var + 1e-5f);
  int h = g & 15;
  float w = gw[h * 64 + lane], bb = gb[h * 64 + lane];
  dst[(size_t)g * 64 + lane] =
      __float2half(((v - mean) * rs * w + bb) * (1.f - lam_init_p[0]));
}

// ---------------------------------------------------------------------------
extern "C" void kernel_launch(void* const* d_in, const int* in_sizes, int n_in,
                              void* d_out, int out_size, void* d_ws,
                              size_t ws_size, hipStream_t stream) {
  const float* x = (const float*)d_in[0];
  const float* Wq = (const float*)d_in[1];
  const float* Wk = (const float*)d_in[2];
  const float* Wv = (const float*)d_in[3];
  const float* Wo = (const float*)d_in[4];
  const float* lq1 = (const float*)d_in[5];
  const float* lk1 = (const float*)d_in[6];
  const float* lq2 = (const float*)d_in[7];
  const float* lk2 = (const float*)d_in[8];
  const float* lam_init = (const float*)d_in[9];
  const float* gnw = (const float*)d_in[10];
  const float* gnb = (const float*)d_in[11];
  float* out = (float*)d_out;

  __half* q_h = (__half*)d_ws;          // region A
  __half* k_h = q_h + 8388608;          // region B
  __half* vt_h = k_h + 8388608;         // region C
  __half* WqT = k_h;                    // B[0:2097152)  (dead after q-GEMM)
  __half* WkT = vt_h;                   // C[0:2097152)  (dead after k-GEMM)
  float2* tab = (float2*)(vt_h + 2097152);  // C[2097152:2359296) fp32 pairs
  __half* WoT = q_h;                    // A[0:1048576)  (q dead after attn)
  __half* gn_h = q_h + 1048576;         // A[1048576:5242880)

  dim3 blk(256);
  // fused prep: Wq/Wk transposes + rope table (1 dispatch)
  prep_kernel<<<2304, blk, 0, stream>>>(Wq, Wk, WqT, WkT, tab);
  // projections (R14: async fragment-major staging); MODE 1 folds scale*log2e
  mfma_gemm<1><<<dim3(32, 32), blk, 0, stream>>>(x, WqT, q_h, tab);
  mfma_gemm<0><<<dim3(32, 32), blk, 0, stream>>>(x, WkT, k_h, tab);
  mfma_gemm<2><<<dim3(16, 32), blk, 0, stream>>>(x, Wv, vt_h, nullptr);
  // differential attention -> d_out (R13 async staging, measured 95.2us)
  attn_kernel<<<dim3(16, 32), blk, 0, stream>>>(q_h, k_h, vt_h, out, lq1, lk1,
                                                lq2, lk2, lam_init);
  // fused GroupNorm + Wo transpose (1 dispatch)
  gn_wt_kernel<<<16896, blk, 0, stream>>>(out, gn_h, gnw, gnb, lam_init, Wo,
                                          WoT);
  // output projection: gn_h @ WoT -> d_out
  mfma_gemm<3><<<dim3(16, 32), blk, 0, stream>>>(gn_h, WoT, out, nullptr);
}

// Round 15
// 324.083 us; speedup vs baseline: 1.2609x; 1.2609x over previous
//
#include <hip/hip_runtime.h>
#include <hip/hip_fp16.h>
#include <math.h>

#define NH     16
#define HD     64
#define S_LEN  2048
#define THD_   1024
// exp(s*0.125) = exp2(s * 0.125 * log2(e))
#define SCALE_LOG2E 0.18033688011112042f

typedef __fp16 f16x8 __attribute__((ext_vector_type(8)));
typedef __fp16 f16x4 __attribute__((ext_vector_type(4)));
typedef __fp16 f16x2 __attribute__((ext_vector_type(2)));
typedef float  f32x4 __attribute__((ext_vector_type(4)));

#define GLDS16(src, dst)                                                      \
  __builtin_amdgcn_global_load_lds(                                           \
      (const __attribute__((address_space(1))) unsigned int*)(const void*)(src), \
      (__attribute__((address_space(3))) unsigned int*)(void*)(dst), 16, 0, 0)

// ws layout (half-elements; total 41,943,040 B, proven safe):
//   region A @ 0        : q_h  8,388,608   [b][comp][h][s][hd]  (PRE-SCALED by SCALE_LOG2E)
//   region B @ 8388608  : k_h  8,388,608   same layout (unscaled)
//   region C @ 16777216 : vt_h 4,194,304   [b][h][hd][s]
// time-shared:
//   WqT fp16 @ B[0:2097152)        (dead once q-GEMM done; k-GEMM overwrites)
//   WkT fp16 @ C[0:2097152)        (dead once k-GEMM done; v-GEMM overwrites)
//   rope tab fp32[2048][32][2] @ C[2097152:2359296) (dead before v-GEMM)
//   WoT @ A[0:1048576), gn_h @ A[1048576:5242880)   (A dead after attn)

// ---------------------------------------------------------------------------
// Shared weight-transpose body: W[k][n] fp32 -> WT[n][k] fp16.
// ---------------------------------------------------------------------------
__device__ inline void wt_body(const float* __restrict__ W,
                               __half* __restrict__ WT, int id, int nmask,
                               int nshift) {
  int n = id & nmask;
  int k8 = (id >> nshift) * 8;
  int N = nmask + 1;
  f16x8 h;
#pragma unroll
  for (int j = 0; j < 8; ++j)
    h[j] = (__fp16)W[(size_t)(k8 + j) * N + n];
  *(f16x8*)(WT + (size_t)n * 1024 + k8) = h;
}

// ---------------------------------------------------------------------------
// Fused prep: blocks [0,1024) transpose Wq; [1024,2048) transpose Wk;
// [2048,2304) fill the RoPE cos/sin table tab[s][p] (2048 x 32).
// ---------------------------------------------------------------------------
__global__ __launch_bounds__(256) void prep_kernel(
    const float* __restrict__ Wq, const float* __restrict__ Wk,
    __half* __restrict__ WqT, __half* __restrict__ WkT,
    float2* __restrict__ tab) {
  int bid = blockIdx.x;
  int t = threadIdx.x;
  if (bid < 1024) {
    wt_body(Wq, WqT, bid * 256 + t, 2047, 11);
  } else if (bid < 2048) {
    wt_body(Wk, WkT, (bid - 1024) * 256 + t, 2047, 11);
  } else {
    int id = (bid - 2048) * 256 + t;  // 65536
    int p = id & 31;
    int s = id >> 5;
    float inv = expf(-0.28782313662425574f * (float)p);
    float sn, cs;
    sincosf((float)s * inv, &sn, &cs);
    tab[id] = make_float2(cs, sn);
  }
}

// ---------------------------------------------------------------------------
// fp16 MFMA GEMM (R6 PROVEN CONFIG, restored after R14 regression: the async
// rewrite's 40,960B LDS x 4 blocks/CU = exactly 160KB hit an occupancy
// cliff, and single-buffer async exposes full latency -- no compute window).
// 128m x 64n tile, BK=64; wave w: rows [w*32,w*32+32) x 64 cols.
// MODE 0: A = x fp32 (cast in staging), B = WT fp16; fused-RoPE epilogue
// MODE 1: MODE 0 + output scaled by SCALE_LOG2E (q path)
// MODE 2: A = x fp32, B = raw Wv fp32 column gather; fp16 to vt [b][h][hd][s]
// ---------------------------------------------------------------------------
template <int MODE>
__global__ __launch_bounds__(256) void mfma_gemm(const void* __restrict__ Ap,
                                                 const void* __restrict__ Bp,
                                                 void* __restrict__ Cp,
                                                 const float2* __restrict__ tab) {
  __shared__ __fp16 As[128][72];
  __shared__ __fp16 Bs[64][72];
  const int t = threadIdx.x;
  const int w = t >> 6, lane = t & 63;
  const int quad = lane >> 4, lqi = lane & 15;
  const int wm = w * 32;
  const int n0 = blockIdx.x * 64, m0 = blockIdx.y * 128;

  f32x4 acc[2][4];
#pragma unroll
  for (int mt = 0; mt < 2; ++mt)
#pragma unroll
    for (int nt = 0; nt < 4; ++nt) acc[mt][nt] = (f32x4){0.f, 0.f, 0.f, 0.f};

  const int srow = t >> 3;         // staging row base (0..31)
  const int sc8 = (t & 7) * 8;     // staging col (halves)
  const int gn_ = t & 63;          // gather: n within tile
  const int gk0 = (t >> 6) * 8;    // gather: k base (0,8,16,24)

  for (int k0 = 0; k0 < 1024; k0 += 64) {
    if (k0) __syncthreads();
    // ---- A staging ----
    {
      const float* A32 = (const float*)Ap;
#pragma unroll
      for (int p = 0; p < 4; ++p) {
        int row = srow + 32 * p;
        const float* src = A32 + (size_t)(m0 + row) * 1024 + k0 + sc8;
        float4 u = *(const float4*)src;
        float4 v = *(const float4*)(src + 4);
        f16x8 h;
        h[0] = (__fp16)u.x; h[1] = (__fp16)u.y;
        h[2] = (__fp16)u.z; h[3] = (__fp16)u.w;
        h[4] = (__fp16)v.x; h[5] = (__fp16)v.y;
        h[6] = (__fp16)v.z; h[7] = (__fp16)v.w;
        *(f16x8*)&As[row][sc8] = h;
      }
    }
    // ---- B staging ----
    if (MODE == 2) {
      const float* B32 = (const float*)Bp;  // Wv row-major [k][1024]
#pragma unroll
      for (int p = 0; p < 2; ++p) {
        int kc = gk0 + 32 * p;
        f16x8 h;
#pragma unroll
        for (int j = 0; j < 8; ++j)
          h[j] = (__fp16)B32[(size_t)(k0 + kc + j) * 1024 + n0 + gn_];
        *(f16x8*)&Bs[gn_][kc] = h;
      }
    } else {
      const __half* B16 = (const __half*)Bp;  // WT [n][k]
      if (srow < 32) {
#pragma unroll
        for (int p = 0; p < 2; ++p) {
          int row = srow + 32 * p;
          *(f16x8*)&Bs[row][sc8] =
              *(const f16x8*)(B16 + (size_t)(n0 + row) * 1024 + k0 + sc8);
        }
      }
    }
    __syncthreads();
    // ---- MFMA ----
#pragma unroll
    for (int ks = 0; ks < 2; ++ks) {
      f16x8 af[2], bf[4];
#pragma unroll
      for (int mt = 0; mt < 2; ++mt)
        af[mt] = *(const f16x8*)&As[wm + mt * 16 + lqi][ks * 32 + quad * 8];
#pragma unroll
      for (int nt = 0; nt < 4; ++nt)
        bf[nt] = *(const f16x8*)&Bs[nt * 16 + lqi][ks * 32 + quad * 8];
#pragma unroll
      for (int mt = 0; mt < 2; ++mt)
#pragma unroll
        for (int nt = 0; nt < 4; ++nt)
          acc[mt][nt] = __builtin_amdgcn_mfma_f32_16x16x32_f16(
              af[mt], bf[nt], acc[mt][nt], 0, 0, 0);
    }
  }

  // ---- epilogue ----
  const int b = m0 >> 11;
  const int s0 = (m0 & 2047) + wm + quad * 4;
  if (MODE == 0 || MODE == 1) {
    __half* dst = (__half*)Cp;
    const int comp = n0 >> 10, hh = (n0 >> 6) & 15;
    __half* base = dst + ((size_t)(b * 2 + comp) * NH + hh) * (size_t)S_LEN * HD;
#pragma unroll
    for (int nt = 0; nt < 2; ++nt) {
      int p = nt * 16 + lqi;
#pragma unroll
      for (int mt = 0; mt < 2; ++mt) {
#pragma unroll
        for (int i = 0; i < 4; ++i) {
          int s = s0 + mt * 16 + i;
          float2 cs = tab[s * 32 + p];
          float x1 = acc[mt][nt][i], x2 = acc[mt][nt + 2][i];
          float y1 = x1 * cs.x - x2 * cs.y;
          float y2 = x2 * cs.x + x1 * cs.y;
          if (MODE == 1) { y1 *= SCALE_LOG2E; y2 *= SCALE_LOG2E; }
          base[(size_t)s * HD + p] = __float2half(y1);
          base[(size_t)s * HD + p + 32] = __float2half(y2);
        }
      }
    }
  } else {
    __half* vt = (__half*)Cp;
    const int hh = n0 >> 6;
#pragma unroll
    for (int nt = 0; nt < 4; ++nt) {
      int hd = nt * 16 + lqi;
      __half* base = vt + (((size_t)b * NH + hh) * HD + hd) * S_LEN;
#pragma unroll
      for (int mt = 0; mt < 2; ++mt) {
        f16x4 hv;
#pragma unroll
        for (int i = 0; i < 4; ++i) hv[i] = (__fp16)acc[mt][nt][i];
        *(f16x4*)(base + s0 + mt * 16) = hv;
      }
    }
  }
}

// ---------------------------------------------------------------------------
// o-GEMM (R15): async fragment-major staging, all-fp16 -- the ONE mode where
// m97's global_load_lds recipe maps with no fp32 inflation.  LDS 24KB
// (A 16KB + B 8KB; far from R14's 40,960B x 4 = 160KB occupancy cliff).
// Each 1KB chunk = one MFMA fragment tile in lane order: async dst is
// wave-uniform + lane*16B, fragment reads lane-linear (conflict-free).
// C = gn_h(4096x1024 fp16) @ WoT^T -> fp32 row-major d_out.
// ---------------------------------------------------------------------------
__global__ __launch_bounds__(256) void mfma_gemm_o(
    const __half* __restrict__ Ap, const __half* __restrict__ Bp,
    float* __restrict__ Cp) {
  __shared__ __half As16[8][2][64][8];  // [mt2][ks][lane][8] = 16 KB
  __shared__ __half Bs[4][2][64][8];    // [nt2][ks][lane][8] = 8 KB
  const int t = threadIdx.x;
  const int w = t >> 6, lane = t & 63;
  const int quad = lane >> 4, lqi = lane & 15;
  const int n0 = blockIdx.x * 64, m0 = blockIdx.y * 128;

  f32x4 acc[2][4];
#pragma unroll
  for (int mt = 0; mt < 2; ++mt)
#pragma unroll
    for (int nt = 0; nt < 4; ++nt) acc[mt][nt] = (f32x4){0.f, 0.f, 0.f, 0.f};

  for (int k0 = 0; k0 < 1024; k0 += 64) {
    if (k0) __syncthreads();
    // ---- async staging: 16 A chunks + 8 B chunks, 6 per wave ----
#pragma unroll
    for (int ci = 0; ci < 6; ++ci) {
      int c = w + ci * 4;
      if (c < 16) {
        int mt2 = c >> 1, ks = c & 1;
        GLDS16(Ap + (size_t)(m0 + mt2 * 16 + lqi) * 1024 + k0 + ks * 32 +
                   quad * 8,
               &As16[mt2][ks][0][0]);
      } else {
        int cc = c - 16, nt2 = cc >> 1, ks = cc & 1;
        GLDS16(Bp + (size_t)(n0 + nt2 * 16 + lqi) * 1024 + k0 + ks * 32 +
                   quad * 8,
               &Bs[nt2][ks][0][0]);
      }
    }
    __syncthreads();
    // ---- MFMA: fragment reads lane-linear ----
#pragma unroll
    for (int ks = 0; ks < 2; ++ks) {
      f16x8 af[2], bf[4];
#pragma unroll
      for (int mt = 0; mt < 2; ++mt)
        af[mt] = *(const f16x8*)&As16[w * 2 + mt][ks][lane][0];
#pragma unroll
      for (int nt = 0; nt < 4; ++nt)
        bf[nt] = *(const f16x8*)&Bs[nt][ks][lane][0];
#pragma unroll
      for (int mt = 0; mt < 2; ++mt)
#pragma unroll
        for (int nt = 0; nt < 4; ++nt)
          acc[mt][nt] = __builtin_amdgcn_mfma_f32_16x16x32_f16(
              af[mt], bf[nt], acc[mt][nt], 0, 0, 0);
    }
  }

  // ---- epilogue: fp32 row-major ----
#pragma unroll
  for (int mt = 0; mt < 2; ++mt)
#pragma unroll
    for (int i = 0; i < 4; ++i) {
      int m = m0 + w * 32 + mt * 16 + quad * 4 + i;
#pragma unroll
      for (int nt = 0; nt < 4; ++nt)
        Cp[(size_t)m * 1024 + n0 + nt * 16 + lqi] = acc[mt][nt][i];
    }
}

// ---------------------------------------------------------------------------
// Differential attention, R13 (MEASURED WIN, unchanged): async global->LDS
// staging via global_load_lds width=16; 108.5 -> 95.2us, MfmaUtil 26->30.7,
// traffic invariant.  K dst wave-uniform + lane*16B; V linear LDS dst with
// XOR swizzle moved into the per-lane GLOBAL source address; read-side
// swizzle unchanged.  One barrier/kt; register-P x32 PV via custom key
// enumeration; scale folded into q.  LDS 48KB, 2 blocks/CU.
// ---------------------------------------------------------------------------
__global__ __launch_bounds__(256, 2) void attn_kernel(
    const __half* __restrict__ q_h, const __half* __restrict__ k_h,
    const __half* __restrict__ vt_h, float* __restrict__ out,
    const float* __restrict__ lq1, const float* __restrict__ lk1,
    const float* __restrict__ lq2, const float* __restrict__ lk2,
    const float* __restrict__ lam_init_p) {
  // K: 16 chunks x 512 halves, chunk = str*8 + mt*2 + ks, addr lane*8.
  // V: [hd 0..63][key 0..63], XOR-swizzled 16B slots within each 128B row
  //    (swizzle applied via the global source address; LDS write is linear).
  __shared__ __half Ks[2][16][512];      // 32 KB
  __shared__ __half Vs[2][64][64];       // 16 KB

  const int t = threadIdx.x;
  const int w = t >> 6, lane = t & 63;
  const int quad = lane >> 4, lqi = lane & 15;
  const int r7 = lane & 7;
  const int qt = blockIdx.x;   // 0..15 (128-query tiles)
  const int bh = blockIdx.y;   // 0..31
  const int b = bh >> 4, h = bh & 15;

  const size_t c1 = ((size_t)(b * 2 + 0) * NH + h) * (size_t)S_LEN * HD;
  const size_t c2 = ((size_t)(b * 2 + 1) * NH + h) * (size_t)S_LEN * HD;
  const size_t vtb = ((size_t)b * NH + h) * (size_t)HD * S_LEN;
  const int q0 = qt * 128 + w * 32;

  f16x8 qf[2][2][2];  // [stream][nt][ks]; q pre-scaled by SCALE_LOG2E
#pragma unroll
  for (int nt = 0; nt < 2; ++nt)
#pragma unroll
    for (int ks = 0; ks < 2; ++ks) {
      size_t a = (size_t)(q0 + nt * 16 + lqi) * HD + ks * 32 + quad * 8;
      qf[0][nt][ks] = *(const f16x8*)(q_h + c1 + a);
      qf[1][nt][ks] = *(const f16x8*)(q_h + c2 + a);
    }

  f32x4 O[2][4][2];  // [stream][hd-chunk][nt]
#pragma unroll
  for (int s = 0; s < 2; ++s)
#pragma unroll
    for (int hm = 0; hm < 4; ++hm)
#pragma unroll
      for (int nt = 0; nt < 2; ++nt) O[s][hm][nt] = (f32x4){0.f, 0.f, 0.f, 0.f};
  float lsum[2][2] = {{0.f, 0.f}, {0.f, 0.f}};

  // async staging: 24 chunks (16 K + 8 V); wave w owns c = w + ci*4.
  auto stage = [&](int c, int k0, int buf) {
    const __half* src;
    __half* dst;
    if (c < 16) {
      int str = c >> 3, mt = (c >> 1) & 3, ks = c & 1;
      src = k_h + (str ? c2 : c1) + (size_t)(k0 + mt * 16 + lqi) * HD +
            ks * 32 + quad * 8;
      dst = &Ks[buf][c][0];
    } else {
      int cc = c - 16;  // V chunk: rows [cc*8, cc*8+8), 64 keys
      src = vt_h + vtb + (size_t)(cc * 8 + (lane >> 3)) * S_LEN + k0 +
            ((lane & 7) ^ (lane >> 3)) * 8;
      dst = &Vs[buf][cc * 8][0];
    }
    GLDS16(src, dst);
  };

  // prologue: stage tile 0 into buffer 0
#pragma unroll
  for (int ci = 0; ci < 6; ++ci) stage(w + ci * 4, 0, 0);
  __syncthreads();

  for (int kt = 0; kt < 32; ++kt) {
    const int cur = kt & 1;
    if (kt < 31) {  // fire-and-forget async loads for tile kt+1
#pragma unroll
      for (int ci = 0; ci < 6; ++ci) stage(w + ci * 4, (kt + 1) * 64, cur ^ 1);
    }

#pragma unroll
    for (int g = 0; g < 2; ++g) {  // 32-key groups (score tiles 2g, 2g+1)
      // ---- V fragments in permuted key order (2 b64 each, swizzle-read) ---
      f16x8 vf[4];
#pragma unroll
      for (int hm = 0; hm < 4; ++hm) {
        const __half* vrow = &Vs[cur][hm * 16 + lqi][0];
        int s0 = (g * 4 + (quad >> 1)) ^ r7;      // keys g*32 + quad*4 ..
        int s1 = (g * 4 + 2 + (quad >> 1)) ^ r7;  // keys g*32+16 + quad*4 ..
        union { f16x8 v8; f16x4 v4[2]; } u;
        u.v4[0] = *(const f16x4*)(vrow + s0 * 8 + (quad & 1) * 4);
        u.v4[1] = *(const f16x4*)(vrow + s1 * 8 + (quad & 1) * 4);
        vf[hm] = u.v8;
      }
      // ---- scores + exp for tiles 2g and 2g+1; B-frag stays in-lane ----
      f16x8 bfrag[2][2];
#pragma unroll
      for (int str = 0; str < 2; ++str) {
        f16x8 kf00 = *(const f16x8*)&Ks[cur][str * 8 + g * 4 + 0][lane * 8];
        f16x8 kf01 = *(const f16x8*)&Ks[cur][str * 8 + g * 4 + 1][lane * 8];
        f16x8 kf10 = *(const f16x8*)&Ks[cur][str * 8 + g * 4 + 2][lane * 8];
        f16x8 kf11 = *(const f16x8*)&Ks[cur][str * 8 + g * 4 + 3][lane * 8];
#pragma unroll
        for (int nt = 0; nt < 2; ++nt) {
          f32x4 sa = (f32x4){0.f, 0.f, 0.f, 0.f};
          f32x4 sb = (f32x4){0.f, 0.f, 0.f, 0.f};
          sa = __builtin_amdgcn_mfma_f32_16x16x32_f16(kf00, qf[str][nt][0], sa,
                                                      0, 0, 0);
          sa = __builtin_amdgcn_mfma_f32_16x16x32_f16(kf01, qf[str][nt][1], sa,
                                                      0, 0, 0);
          sb = __builtin_amdgcn_mfma_f32_16x16x32_f16(kf10, qf[str][nt][0], sb,
                                                      0, 0, 0);
          sb = __builtin_amdgcn_mfma_f32_16x16x32_f16(kf11, qf[str][nt][1], sb,
                                                      0, 0, 0);
          float ea0 = __builtin_amdgcn_exp2f(sa[0]);
          float ea1 = __builtin_amdgcn_exp2f(sa[1]);
          float ea2 = __builtin_amdgcn_exp2f(sa[2]);
          float ea3 = __builtin_amdgcn_exp2f(sa[3]);
          float eb0 = __builtin_amdgcn_exp2f(sb[0]);
          float eb1 = __builtin_amdgcn_exp2f(sb[1]);
          float eb2 = __builtin_amdgcn_exp2f(sb[2]);
          float eb3 = __builtin_amdgcn_exp2f(sb[3]);
          lsum[str][nt] += ((ea0 + ea1) + (ea2 + ea3)) +
                           ((eb0 + eb1) + (eb2 + eb3));
          union { f16x8 v; f16x2 h2[4]; } pu;
          pu.h2[0] = __builtin_amdgcn_cvt_pkrtz(ea0, ea1);
          pu.h2[1] = __builtin_amdgcn_cvt_pkrtz(ea2, ea3);
          pu.h2[2] = __builtin_amdgcn_cvt_pkrtz(eb0, eb1);
          pu.h2[3] = __builtin_amdgcn_cvt_pkrtz(eb2, eb3);
          bfrag[str][nt] = pu.v;
        }
      }
      // ---- PV: full-rate x32 MFMAs, P fragment straight from registers ----
#pragma unroll
      for (int hm = 0; hm < 4; ++hm)
#pragma unroll
        for (int str = 0; str < 2; ++str)
#pragma unroll
          for (int nt = 0; nt < 2; ++nt)
            O[str][hm][nt] = __builtin_amdgcn_mfma_f32_16x16x32_f16(
                vf[hm], bfrag[str][nt], O[str][hm][nt], 0, 0, 0);
    }

    if (kt < 31) __syncthreads();  // drains vmcnt -> tile kt+1 visible
  }

  const float lam0 = lam_init_p[0];
  const float lam = expf(lq1[h] * lk1[h]) - expf(lq2[h] * lk2[h]) + lam0;
#pragma unroll
  for (int str = 0; str < 2; ++str)
#pragma unroll
    for (int nt = 0; nt < 2; ++nt) {
      float v = lsum[str][nt];
      v += __shfl_xor(v, 16);
      v += __shfl_xor(v, 32);
      lsum[str][nt] = v;
    }
#pragma unroll
  for (int nt = 0; nt < 2; ++nt) {
    float il1 = 1.f / lsum[0][nt];
    float il2 = lam / lsum[1][nt];
    int q = q0 + nt * 16 + lqi;
#pragma unroll
    for (int hm = 0; hm < 4; ++hm) {
      f32x4 o;
#pragma unroll
      for (int i = 0; i < 4; ++i)
        o[i] = O[0][hm][nt][i] * il1 - O[1][hm][nt][i] * il2;
      *(f32x4*)(out + ((size_t)(b * S_LEN + q)) * THD_ + h * HD + hm * 16 +
                quad * 4) = o;
    }
  }
}

// ---------------------------------------------------------------------------
// Fused GroupNorm + Wo transpose. Blocks [0,16384): GroupNorm over 64-elem
// head groups (d_out fp32 -> gn_h fp16, * (1-lambda_init)); blocks
// [16384,16896): transpose Wo fp32 -> WoT fp16 [n][k].
// ---------------------------------------------------------------------------
__global__ __launch_bounds__(256) void gn_wt_kernel(
    const float* __restrict__ src, __half* __restrict__ dst,
    const float* __restrict__ gw, const float* __restrict__ gb,
    const float* __restrict__ lam_init_p, const float* __restrict__ Wo,
    __half* __restrict__ WoT) {
  if (blockIdx.x >= 16384) {
    wt_body(Wo, WoT, (blockIdx.x - 16384) * 256 + threadIdx.x, 1023, 10);
    return;
  }
  int g = blockIdx.x * 4 + (threadIdx.x >> 6);
  int lane = threadIdx.x & 63;
  float v = src[(size_t)g * 64 + lane];
  float s = v, sq = v * v;
#pragma unroll
  for (int off = 32; off; off >>= 1) {
    s += __shfl_xor(s, off);
    sq += __shfl_xor(sq, off);
  }
  float mean = s * (1.f / 64.f);
  float var = sq * (1.f / 64.f) - mean * mean;
  float rs = rsqrtf(var + 1e-5f);
  int h = g & 15;
  float w = gw[h * 64 + lane], bb = gb[h * 64 + lane];
  dst[(size_t)g * 64 + lane] =
      __float2half(((v - mean) * rs * w + bb) * (1.f - lam_init_p[0]));
}

// ---------------------------------------------------------------------------
extern "C" void kernel_launch(void* const* d_in, const int* in_sizes, int n_in,
                              void* d_out, int out_size, void* d_ws,
                              size_t ws_size, hipStream_t stream) {
  const float* x = (const float*)d_in[0];
  const float* Wq = (const float*)d_in[1];
  const float* Wk = (const float*)d_in[2];
  const float* Wv = (const float*)d_in[3];
  const float* Wo = (const float*)d_in[4];
  const float* lq1 = (const float*)d_in[5];
  const float* lk1 = (const float*)d_in[6];
  const float* lq2 = (const float*)d_in[7];
  const float* lk2 = (const float*)d_in[8];
  const float* lam_init = (const float*)d_in[9];
  const float* gnw = (const float*)d_in[10];
  const float* gnb = (const float*)d_in[11];
  float* out = (float*)d_out;

  __half* q_h = (__half*)d_ws;          // region A
  __half* k_h = q_h + 8388608;          // region B
  __half* vt_h = k_h + 8388608;         // region C
  __half* WqT = k_h;                    // B[0:2097152)  (dead after q-GEMM)
  __half* WkT = vt_h;                   // C[0:2097152)  (dead after k-GEMM)
  float2* tab = (float2*)(vt_h + 2097152);  // C[2097152:2359296) fp32 pairs
  __half* WoT = q_h;                    // A[0:1048576)  (q dead after attn)
  __half* gn_h = q_h + 1048576;         // A[1048576:5242880)

  dim3 blk(256);
  // fused prep: Wq/Wk transposes + rope table (1 dispatch)
  prep_kernel<<<2304, blk, 0, stream>>>(Wq, Wk, WqT, WkT, tab);
  // projections (R6 proven config); MODE 1 folds scale*log2e
  mfma_gemm<1><<<dim3(32, 32), blk, 0, stream>>>(x, WqT, q_h, tab);
  mfma_gemm<0><<<dim3(32, 32), blk, 0, stream>>>(x, WkT, k_h, tab);
  mfma_gemm<2><<<dim3(16, 32), blk, 0, stream>>>(x, Wv, vt_h, nullptr);
  // differential attention -> d_out (R13 async staging, measured 95.2us)
  attn_kernel<<<dim3(16, 32), blk, 0, stream>>>(q_h, k_h, vt_h, out, lq1, lk1,
                                                lq2, lk2, lam_init);
  // fused GroupNorm + Wo transpose (1 dispatch)
  gn_wt_kernel<<<16896, blk, 0, stream>>>(out, gn_h, gnw, gnb, lam_init, Wo,
                                          WoT);
  // output projection (R15: async fragment-major, 24KB LDS)
  mfma_gemm_o<<<dim3(16, 32), blk, 0, stream>>>(gn_h, WoT, out);
}